// Round 1
// baseline (4694.154 us; speedup 1.0000x reference)
//
#include <hip/hip_runtime.h>
#include <cstdint>
#include <cstddef>

#define VOCAB 32000
#define HID   1024
#define OUTV  32000
#define BB    8
#define TT    256
#define MM    (BB*TT)   // 2048

typedef __attribute__((ext_vector_type(4))) float          f32x4;
typedef __attribute__((ext_vector_type(8))) __bf16         bf16x8;
typedef __attribute__((ext_vector_type(8))) unsigned short u16x8;
typedef __attribute__((ext_vector_type(4))) unsigned short u16x4;

__device__ __forceinline__ unsigned short f2bf(float f) {
    uint32_t u = __builtin_bit_cast(uint32_t, f);
    u += 0x7FFFu + ((u >> 16) & 1u);   // RNE
    return (unsigned short)(u >> 16);
}

// ---------------- K0: f32 -> bf16 convert (W_out, W_ih) ----------------
__global__ __launch_bounds__(256) void cvt_bf16_kernel(const float* __restrict__ src,
                                                       unsigned short* __restrict__ dst, int n) {
    int i = (blockIdx.x * 256 + threadIdx.x) * 4;
    const int stride = gridDim.x * 256 * 4;
    for (; i < n; i += stride) {
        f32x4 v = *(const f32x4*)(src + i);
        u16x4 o = { f2bf(v[0]), f2bf(v[1]), f2bf(v[2]), f2bf(v[3]) };
        *(u16x4*)(dst + i) = o;
    }
}

// ---------------- K1: xp[m][j] = embed[tok(m)] @ W_ih^T + b_ih (bf16 MFMA) ----------------
// m = t*BB + b. grid (HID/128, MM/128), block 256 (4 waves, each 64x64).
__global__ __launch_bounds__(256) void xp_gemm_kernel(
    const int* __restrict__ x, const float* __restrict__ embed,
    const unsigned short* __restrict__ WihB, const float* __restrict__ b_ih,
    float* __restrict__ xp)
{
    __shared__ unsigned short Alds[128][40];   // +8 pad: frag ds_reads land uniform on 16B windows
    __shared__ unsigned short Blds[128][40];
    const int tid  = threadIdx.x;
    const int n0   = blockIdx.x * 128;
    const int m0   = blockIdx.y * 128;
    const int wave = tid >> 6, lane = tid & 63;
    const int wr = wave >> 1, wc = wave & 1;
    const int fr = lane & 15, fo = (lane >> 4) * 8;

    const int srow = tid >> 1;
    const int sseg = (tid & 1) * 16;
    const int mrow = m0 + srow;
    const int tok  = x[(mrow & 7) * TT + (mrow >> 3)];   // x[b][t], b=m&7, t=m>>3
    const float* aptr          = embed + (size_t)tok * HID + sseg;
    const unsigned short* bptr = WihB  + (size_t)(n0 + srow) * HID + sseg;

    f32x4 acc[4][4] = {};

    for (int k0 = 0; k0 < HID; k0 += 32) {
        f32x4 v0 = *(const f32x4*)(aptr + k0);
        f32x4 v1 = *(const f32x4*)(aptr + k0 + 4);
        f32x4 v2 = *(const f32x4*)(aptr + k0 + 8);
        f32x4 v3 = *(const f32x4*)(aptr + k0 + 12);
        u16x8 aw0 = { f2bf(v0[0]), f2bf(v0[1]), f2bf(v0[2]), f2bf(v0[3]),
                      f2bf(v1[0]), f2bf(v1[1]), f2bf(v1[2]), f2bf(v1[3]) };
        u16x8 aw1 = { f2bf(v2[0]), f2bf(v2[1]), f2bf(v2[2]), f2bf(v2[3]),
                      f2bf(v3[0]), f2bf(v3[1]), f2bf(v3[2]), f2bf(v3[3]) };
        u16x8 bw0 = *(const u16x8*)(bptr + k0);
        u16x8 bw1 = *(const u16x8*)(bptr + k0 + 8);
        *(u16x8*)&Alds[srow][sseg]     = aw0;
        *(u16x8*)&Alds[srow][sseg + 8] = aw1;
        *(u16x8*)&Blds[srow][sseg]     = bw0;
        *(u16x8*)&Blds[srow][sseg + 8] = bw1;
        __syncthreads();

        u16x8 ar[4], br[4];
        #pragma unroll
        for (int mi = 0; mi < 4; mi++) ar[mi] = *(const u16x8*)&Alds[wr*64 + mi*16 + fr][fo];
        #pragma unroll
        for (int ni = 0; ni < 4; ni++) br[ni] = *(const u16x8*)&Blds[wc*64 + ni*16 + fr][fo];
        #pragma unroll
        for (int mi = 0; mi < 4; mi++)
            #pragma unroll
            for (int ni = 0; ni < 4; ni++)
                acc[mi][ni] = __builtin_amdgcn_mfma_f32_16x16x32_bf16(
                    __builtin_bit_cast(bf16x8, ar[mi]), __builtin_bit_cast(bf16x8, br[ni]),
                    acc[mi][ni], 0, 0, 0);
        __syncthreads();
    }

    #pragma unroll
    for (int mi = 0; mi < 4; mi++) {
        const int row = m0 + wr*64 + mi*16 + (lane >> 4) * 4;  // D: col=lane&15, row=(lane>>4)*4+r
        #pragma unroll
        for (int ni = 0; ni < 4; ni++) {
            const int col = n0 + wc*64 + ni*16 + fr;
            const float bi = b_ih[col];
            #pragma unroll
            for (int r = 0; r < 4; r++)
                xp[(size_t)(row + r) * HID + col] = acc[mi][ni][r] + bi;
        }
    }
}

// ---------------- K2: persistent scan. 256 WGs (32 per batch), W_hh slice in LDS (f32) ----
// Per-batch monotonic barrier via agent-scope atomics; grid==256==CU count -> co-resident.
__global__ __launch_bounds__(256, 1) void scan_kernel(
    const float* __restrict__ W_hh, const float* __restrict__ b_hh,
    const float* __restrict__ xp, float* __restrict__ hbuf,
    unsigned int* __restrict__ cnt, unsigned short* __restrict__ hs,
    float* __restrict__ hfinal)
{
    extern __shared__ float Wl[];   // [32][1024] f32 = 128 KB
    const int tid  = threadIdx.x;
    const int b    = blockIdx.x >> 5;
    const int s    = blockIdx.x & 31;
    const int j0   = s * 32;
    const int wave = tid >> 6, lane = tid & 63;

    {
        const f32x4* wsrc = (const f32x4*)(W_hh + (size_t)j0 * HID);
        f32x4* wdst = (f32x4*)Wl;
        for (int i = tid; i < (32 * HID) / 4; i += 256) wdst[i] = wsrc[i];
    }
    const int   jout = j0 + wave * 8 + lane;                 // valid only for lane<8
    const float bhv  = (lane < 8) ? b_hh[jout] : 0.0f;
    __syncthreads();

    for (int t = 0; t < TT; t++) {
        const int p = t & 1;
        const float* hp = hbuf + p * (BB * HID) + b * HID;
        float*       hn = hbuf + (p ^ 1) * (BB * HID) + b * HID;

        // each lane owns contiguous k-range [lane*16, lane*16+16)
        const f32x4* hp4 = (const f32x4*)(hp + lane * 16);
        f32x4 h0 = hp4[0], h1 = hp4[1], h2 = hp4[2], h3 = hp4[3];

        float res[8];
        #pragma unroll
        for (int q = 0; q < 8; q++) {
            const f32x4* wr4 = (const f32x4*)(Wl + (size_t)(wave*8 + q) * HID + lane * 16);
            f32x4 w0 = wr4[0], w1 = wr4[1], w2 = wr4[2], w3 = wr4[3];
            float a;
            a  = w0[0]*h0[0] + w0[1]*h0[1] + w0[2]*h0[2] + w0[3]*h0[3];
            a += w1[0]*h1[0] + w1[1]*h1[1] + w1[2]*h1[2] + w1[3]*h1[3];
            a += w2[0]*h2[0] + w2[1]*h2[1] + w2[2]*h2[2] + w2[3]*h2[3];
            a += w3[0]*h3[0] + w3[1]*h3[1] + w3[2]*h3[2] + w3[3]*h3[3];
            #pragma unroll
            for (int off = 32; off >= 1; off >>= 1) a += __shfl_xor(a, off, 64);
            res[q] = a;
        }
        float sum = res[0];
        #pragma unroll
        for (int q = 1; q < 8; q++) sum = (lane == q) ? res[q] : sum;

        if (lane < 8) {
            const float v = tanhf(sum + bhv + xp[(size_t)(t * BB + b) * HID + jout]);
            hn[jout] = v;
            hs[(size_t)(t * BB + b) * HID + jout] = f2bf(v);
            if (t == TT - 1) hfinal[b * HID + jout] = v;
        }

        __syncthreads();                       // all stores drained (barrier implies vmcnt(0))
        if (tid == 0) {
            __builtin_amdgcn_fence(__ATOMIC_RELEASE, "agent");
            __hip_atomic_fetch_add(&cnt[b], 1u, __ATOMIC_RELAXED, __HIP_MEMORY_SCOPE_AGENT);
            const unsigned int tgt = 32u * (unsigned)(t + 1);
            while (__hip_atomic_load(&cnt[b], __ATOMIC_RELAXED, __HIP_MEMORY_SCOPE_AGENT) < tgt)
                __builtin_amdgcn_s_sleep(1);
            __builtin_amdgcn_fence(__ATOMIC_ACQUIRE, "agent");
        }
        __syncthreads();
    }
}

// ---------------- K3: out[b][t][v] = hs[m] @ W_out^T + b_out (bf16 MFMA) ----------------
__global__ __launch_bounds__(256) void out_gemm_kernel(
    const unsigned short* __restrict__ hs, const unsigned short* __restrict__ WoutB,
    const float* __restrict__ b_out, float* __restrict__ out)
{
    __shared__ unsigned short Alds[128][40];
    __shared__ unsigned short Blds[128][40];
    const int tid  = threadIdx.x;
    const int n0   = blockIdx.x * 128;
    const int m0   = blockIdx.y * 128;
    const int wave = tid >> 6, lane = tid & 63;
    const int wr = wave >> 1, wc = wave & 1;
    const int fr = lane & 15, fo = (lane >> 4) * 8;

    const int srow = tid >> 1;
    const int sseg = (tid & 1) * 16;
    const unsigned short* aptr = hs    + (size_t)(m0 + srow) * HID + sseg;
    const unsigned short* bptr = WoutB + (size_t)(n0 + srow) * HID + sseg;

    f32x4 acc[4][4] = {};

    for (int k0 = 0; k0 < HID; k0 += 32) {
        u16x8 aw0 = *(const u16x8*)(aptr + k0);
        u16x8 aw1 = *(const u16x8*)(aptr + k0 + 8);
        u16x8 bw0 = *(const u16x8*)(bptr + k0);
        u16x8 bw1 = *(const u16x8*)(bptr + k0 + 8);
        *(u16x8*)&Alds[srow][sseg]     = aw0;
        *(u16x8*)&Alds[srow][sseg + 8] = aw1;
        *(u16x8*)&Blds[srow][sseg]     = bw0;
        *(u16x8*)&Blds[srow][sseg + 8] = bw1;
        __syncthreads();

        u16x8 ar[4], br[4];
        #pragma unroll
        for (int mi = 0; mi < 4; mi++) ar[mi] = *(const u16x8*)&Alds[wr*64 + mi*16 + fr][fo];
        #pragma unroll
        for (int ni = 0; ni < 4; ni++) br[ni] = *(const u16x8*)&Blds[wc*64 + ni*16 + fr][fo];
        #pragma unroll
        for (int mi = 0; mi < 4; mi++)
            #pragma unroll
            for (int ni = 0; ni < 4; ni++)
                acc[mi][ni] = __builtin_amdgcn_mfma_f32_16x16x32_bf16(
                    __builtin_bit_cast(bf16x8, ar[mi]), __builtin_bit_cast(bf16x8, br[ni]),
                    acc[mi][ni], 0, 0, 0);
        __syncthreads();
    }

    #pragma unroll
    for (int mi = 0; mi < 4; mi++) {
        const int row = m0 + wr*64 + mi*16 + (lane >> 4) * 4;
        #pragma unroll
        for (int ni = 0; ni < 4; ni++) {
            const int col = n0 + wc*64 + ni*16 + fr;
            const float bo = b_out[col];
            #pragma unroll
            for (int r = 0; r < 4; r++) {
                const int m = row + r;                       // m = t*BB + b
                out[((size_t)(m & 7) * TT + (m >> 3)) * OUTV + col] = acc[mi][ni][r] + bo;
            }
        }
    }
}

extern "C" void kernel_launch(void* const* d_in, const int* in_sizes, int n_in,
                              void* d_out, int out_size, void* d_ws, size_t ws_size,
                              hipStream_t stream) {
    const int*   x     = (const int*)  d_in[0];
    const float* embed = (const float*)d_in[1];
    const float* W_ih  = (const float*)d_in[2];
    const float* b_ih  = (const float*)d_in[3];
    const float* W_hh  = (const float*)d_in[4];
    const float* b_hh  = (const float*)d_in[5];
    const float* W_out = (const float*)d_in[6];
    const float* b_out = (const float*)d_in[7];

    float* out    = (float*)d_out;
    float* hfinal = out + (size_t)MM * OUTV;   // h_final appended after outputs

    // workspace layout (needs ~79 MB)
    char* ws = (char*)d_ws;
    float*          xpb   = (float*)(ws);                        // [2048][1024] f32 = 8 MB
    unsigned short* hsb   = (unsigned short*)(ws + (8u  << 20)); // [2048][1024] bf16 = 4 MB
    float*          hbuf  = (float*)(ws + (12u << 20));          // 2*[8][1024] f32 = 64 KB
    unsigned int*   cnt   = (unsigned int*)(ws + (12u << 20) + 65536); // 8 counters
    unsigned short* WoutB = (unsigned short*)(ws + (13u << 20)); // 62.5 MB
    unsigned short* WihB  = (unsigned short*)(ws + (77u << 20)); // 2 MB

    hipMemsetAsync(ws + (12u << 20), 0, 65536 + 4096, stream);   // h0 = 0, counters = 0

    cvt_bf16_kernel<<<2048, 256, 0, stream>>>(W_out, WoutB, OUTV * HID);
    cvt_bf16_kernel<<<256,  256, 0, stream>>>(W_ih,  WihB,  HID * HID);

    xp_gemm_kernel<<<dim3(HID / 128, MM / 128), 256, 0, stream>>>(x, embed, WihB, b_ih, xpb);

    hipFuncSetAttribute((const void*)scan_kernel,
                        hipFuncAttributeMaxDynamicSharedMemorySize, 32 * HID * 4);
    scan_kernel<<<256, 256, 32 * HID * 4, stream>>>(W_hh, b_hh, xpb, hbuf, cnt, hsb, hfinal);

    out_gemm_kernel<<<dim3(OUTV / 128, MM / 128), 256, 0, stream>>>(hsb, WoutB, b_out, out);
}